// Round 3
// baseline (503.569 us; speedup 1.0000x reference)
//
#include <hip/hip_runtime.h>
#include <cstdint>
#include <cstddef>

// LLAConv2d: per-sample 1x1 conv == 32 independent GEMMs
//   out[b,o,p] = sum_i K[b,o,i] * x[b,i,p],  K[b] = sum_e alpha[b,e]*ke[e]
// B=32, Cin=Cout=64, P=160*160=25600, fp32.
// Floors: HBM ~50us (FETCH ~105MB w/ L3 absorb + WRITE 205MB @6.4TB/s),
//         fp32 VALU ~43us (no fp32 MFMA on CDNA4).
// History: R2 110us = LDS-pipe-bound (768 ds_read_b128/tile = 9.2Kcy vs
//   4.1Kcy FMA/SIMD). R4 150us = lgkmcnt-mixing-bound (s_load k + ds_read x
//   share lgkmcnt, SMEM out-of-order -> lgkmcnt(0) drains each unroll group).
// R5: x read from GLOBAL (vmcnt, coalesced, compiler-pipelined; 4x L2 reuse
//   ~840MB @34.5TB/s = 24us, L2-hot). k from LDS staged once per block, read
//   as 2-distinct-address/wave ds_read_b128 -> 2-way broadcast = free (m136).
//   ZERO barriers in main loop; 1024 blocks (32/sample x 6-7 tiles), 4 blk/CU.

#define PIX 25600
#define CIN 64
#define COUT 64
#define BATCH 32
#define NEXP 8
#define TILE_PX 128
#define TILES_PER_B (PIX / TILE_PX) // 200
#define BLOCKS_PER_B 32
#define GRID (BATCH * BLOCKS_PER_B) // 1024 = 4 blocks/CU, one residency round

__device__ __forceinline__ void load_lds16(const float* g, float* l) {
  // async global->LDS, 16B/lane; global addr per-lane, LDS dst uniform+lane*16
  __builtin_amdgcn_global_load_lds(
      (__attribute__((address_space(1))) void*)(g),
      (__attribute__((address_space(3))) void*)(l), 16, 0, 0);
}

// ---------------- Kernel A: mix kernels, store TRANSPOSED kt[b][i][o] -------
__global__ __launch_bounds__(256) void mix_kernel(
    const float* __restrict__ alpha, const float* __restrict__ ke,
    float* __restrict__ kt) {
  const int b = blockIdx.x >> 3;
  const int seg = blockIdx.x & 7;
  __shared__ float a[NEXP];
  if (threadIdx.x < NEXP) a[threadIdx.x] = alpha[b * NEXP + threadIdx.x];
  __syncthreads();
#pragma unroll
  for (int t = 0; t < 2; t++) {
    const int idx = seg * 512 + t * 256 + threadIdx.x; // idx = o*64 + i
    float s = 0.f;
#pragma unroll
    for (int e = 0; e < NEXP; e++) s += a[e] * ke[e * 4096 + idx];
    const int o = idx >> 6, i = idx & 63;
    kt[b * 4096 + i * 64 + o] = s; // transposed: [i][o]
  }
}

// ---------------- Kernel B: barrier-free 1x1-conv GEMM ----------------------
// Block = (sample b) x (block-in-sample s); handles tiles s, s+32, ... (6-7).
// Thread tile: tc=tid>>5 -> 8 out-channels, tp=tid&31 -> 4 pixels (acc[8][4]).
// k: LDS ks[i][o] (16KB, staged once). Inner-loop reads ks[ii*64+tc*8] =
//    2 distinct addrs/wave (lanes 0-31 one tc, 32-63 the other) -> 2-way
//    broadcast, conflict-free & cheap. Pure-DS lgkm: in-order, counted waits.
// x: global_load_dwordx4 per K-step; lanes 0-31 cover 512B contiguous, lanes
//    32-63 same addrs (coalescer merge). Compiler pipelines via counted vmcnt.
// No __syncthreads after the k-stage one: waves free-run, 16 waves/CU hide
// L2 latency. FMA order identical to R2 (ascending ii) -> bit-exact output.
__global__ __launch_bounds__(256, 4) void conv_kernel(
    const float* __restrict__ x, const float* __restrict__ kt,
    float* __restrict__ out) {
  __shared__ float ks[CIN * COUT]; // [i][o], 16KB

  const int bid = blockIdx.x;
  const int b = bid >> 5;  // sample
  const int s = bid & 31;  // block-in-sample
  const int tid = threadIdx.x;
  const int wave = tid >> 6;
  const int lane = tid & 63;
  const int tc = tid >> 5; // 0..7 (channel group of 8)
  const int tp = tid & 31; // 0..31 (pixel group of 4)

  // Stage ks once: 16KB = 16 wave-instrs; wave w does 4 (each 1KB row-chunk)
  const float* kb = kt + b * 4096;
#pragma unroll
  for (int j = 0; j < 4; j++) {
    const int r = wave * 4 + j;
    load_lds16(kb + r * 256 + lane * 4, &ks[r * 256]);
  }
  __syncthreads(); // single barrier in the whole kernel (drains the stage)

  const float* xb = x + (size_t)b * CIN * PIX;
  float* outb = out + ((size_t)b * COUT + tc * 8) * PIX;
  const float* kp = ks + tc * 8;

  for (int t = s; t < TILES_PER_B; t += BLOCKS_PER_B) {
    const int P0 = t * TILE_PX;

    float acc[8][4];
#pragma unroll
    for (int c = 0; c < 8; c++)
#pragma unroll
      for (int p = 0; p < 4; p++) acc[c][p] = 0.f;

    const float* xp = xb + P0 + tp * 4;
#pragma unroll 8
    for (int ii = 0; ii < CIN; ii++) {
      const float4 xv = *(const float4*)(xp + (size_t)ii * PIX); // global
      const float4 k0 = *(const float4*)(kp + ii * 64);          // LDS bcast
      const float4 k1 = *(const float4*)(kp + ii * 64 + 4);      // LDS bcast
      const float kc[8] = {k0.x, k0.y, k0.z, k0.w, k1.x, k1.y, k1.z, k1.w};
      const float xv4[4] = {xv.x, xv.y, xv.z, xv.w};
#pragma unroll
      for (int c = 0; c < 8; c++)
#pragma unroll
        for (int p = 0; p < 4; p++) acc[c][p] = fmaf(kc[c], xv4[p], acc[c][p]);
    }

    // Epilogue: 8 x float4 stores; lanes sharing tc cover 512B contiguous.
    float* ob = outb + P0 + tp * 4;
#pragma unroll
    for (int c = 0; c < 8; c++) {
      *(float4*)(ob + (size_t)c * PIX) =
          make_float4(acc[c][0], acc[c][1], acc[c][2], acc[c][3]);
    }
  }
}

extern "C" void kernel_launch(void* const* d_in, const int* in_sizes, int n_in,
                              void* d_out, int out_size, void* d_ws,
                              size_t ws_size, hipStream_t stream) {
  const float* x = (const float*)d_in[0];     // [32,64,160,160]
  const float* alpha = (const float*)d_in[1]; // [32,8]
  const float* ke = (const float*)d_in[2];    // [8,64,64,1,1]
  float* out = (float*)d_out;                 // [32,64,160,160]
  float* kt = (float*)d_ws;                   // 32*4096 floats = 512KB scratch

  mix_kernel<<<BATCH * 8, 256, 0, stream>>>(alpha, ke, kt);
  conv_kernel<<<GRID, 256, 0, stream>>>(x, kt, out);
}

// Round 4
// 383.872 us; speedup vs baseline: 1.3118x; 1.3118x over previous
//
#include <hip/hip_runtime.h>
#include <cstdint>
#include <cstddef>

// LLAConv2d: per-sample 1x1 conv == 32 independent GEMMs
//   out[b,o,p] = sum_i K[b,o,i] * x[b,i,p],  K[b] = sum_e alpha[b,e]*ke[e]
// B=32, Cin=Cout=64, P=160*160=25600, fp32.
// Floors: HBM ~50us (measured hbm_bytes 317MB @6.4TB/s), fp32 VALU 43us pure
// FMA (no fp32 MFMA on CDNA4), ~55-60us with addressing overhead.
// History:
//   R2 110us  x+k both LDS: LDS-delivery-bound. 1.5B/FMA vs ~0.66B/FMA
//             sustainable (ds_read_b128 ~12cy writeback even for broadcast)
//             -> VALUBusy capped ~45% (R3 measured 44.8%, model confirmed).
//   R4 150us  k s_load + x ds_read: SMEM and DS share lgkmcnt, SMEM is OOO
//             -> compiler emits lgkmcnt(0) per group, drains ds pipeline.
//   R5 260us  k LDS + x global: compiler collapsed the x pipeline (VGPR=36,
//             zero loads in flight) -> raw L2 latency per K-step.
// R6: ZERO LDS. k via SMEM->SGPR (wave-uniform channel group; 64B/ii/wave,
//   no 64-lane writeback, v_fma takes SGPR operand directly). x via global
//   float4 (1KB/wave coalesced) with EXPLICIT depth-2 prefetch rotation so
//   the schedule can't collapse. lgkmcnt carries only SMEM -> no R4 mixing.
//   No barriers. acc[16][4]=64 VGPR, ~90 total -> 4 waves/SIMD.

#define PIX 25600
#define CIN 64
#define COUT 64
#define BATCH 32
#define NEXP 8
#define TILE_PX 256
#define TILES_PER_B (PIX / TILE_PX) // 100
#define GRID (BATCH * TILES_PER_B)  // 3200 blocks

// ---------------- Kernel A: mix kernels, store kt[b][i][o] ------------------
__global__ __launch_bounds__(256) void mix_kernel(
    const float* __restrict__ alpha, const float* __restrict__ ke,
    float* __restrict__ kt) {
  const int b = blockIdx.x >> 3;
  const int seg = blockIdx.x & 7;
  __shared__ float a[NEXP];
  if (threadIdx.x < NEXP) a[threadIdx.x] = alpha[b * NEXP + threadIdx.x];
  __syncthreads();
#pragma unroll
  for (int t = 0; t < 2; t++) {
    const int idx = seg * 512 + t * 256 + threadIdx.x; // idx = o*64 + i
    float s = 0.f;
#pragma unroll
    for (int e = 0; e < NEXP; e++) s += a[e] * ke[e * 4096 + idx];
    const int o = idx >> 6, i = idx & 63;
    kt[b * 4096 + i * 64 + o] = s; // [b][i][o]: rows of 64 out-chans
  }
}

// ---------------- Kernel B: zero-LDS SGPR-k 1x1-conv GEMM -------------------
// Block = 64ch x 256px tile; 3200 blocks x 256 threads, no barriers.
// Wave w owns out-channels [16w,16w+16); lane owns 4 px.
// k: kt[b][ii][16w..16w+16) is wave-uniform (readfirstlane'd w) -> s_load
//    into SGPRs (s_load_dwordx16 per ii under unroll), kt L2/sL1-resident.
// x: global_load_dwordx4, 64 lanes cover 1KB contiguous per ii; depth-2
//    rotation xa<-xb<-xn keeps >=2 loads in flight per wave; 4 waves/SIMD
//    TLP on top. Loop body has no stores, no LDS -> loads freely hoisted.
// FMA order: ascending ii, fmaf — same reduction order as prior rounds.
__global__ __launch_bounds__(256, 4) void conv_kernel(
    const float* __restrict__ x, const float* __restrict__ kt,
    float* __restrict__ out) {
  const int bid = blockIdx.x;
  const int b = bid / TILES_PER_B;
  const int t = bid - b * TILES_PER_B;
  const int P0 = t * TILE_PX;

  const int lane = threadIdx.x & 63;
  const int w = __builtin_amdgcn_readfirstlane(threadIdx.x >> 6); // ch-group

  const float* xp = x + (size_t)b * CIN * PIX + P0 + lane * 4;
  const float* kb = kt + b * 4096 + w * 16; // uniform; row stride 64 floats

  float acc[16][4];
#pragma unroll
  for (int c = 0; c < 16; c++)
#pragma unroll
    for (int p = 0; p < 4; p++) acc[c][p] = 0.f;

  // depth-2 x prefetch rotation
  float4 xa = *(const float4*)(xp);
  float4 xb = *(const float4*)(xp + PIX);

#pragma unroll 4
  for (int ii = 0; ii < CIN; ii++) {
    const int iin = (ii + 2 < CIN) ? (ii + 2) : (CIN - 1); // clamp: safe addr
    const float4 xn = *(const float4*)(xp + (size_t)iin * PIX);

    const float* kr = kb + ii * 64; // uniform -> s_load
#pragma unroll
    for (int c = 0; c < 16; c++) {
      const float kv = kr[c]; // SGPR; v_fma src0 = SGPR, no moves
      acc[c][0] = fmaf(kv, xa.x, acc[c][0]);
      acc[c][1] = fmaf(kv, xa.y, acc[c][1]);
      acc[c][2] = fmaf(kv, xa.z, acc[c][2]);
      acc[c][3] = fmaf(kv, xa.w, acc[c][3]);
    }
    xa = xb;
    xb = xn;
  }

  // Epilogue: 16 x float4 stores; 64 lanes cover 1KB contiguous per channel.
  float* ob = out + ((size_t)b * COUT + w * 16) * PIX + P0 + lane * 4;
#pragma unroll
  for (int c = 0; c < 16; c++) {
    *(float4*)(ob + (size_t)c * PIX) =
        make_float4(acc[c][0], acc[c][1], acc[c][2], acc[c][3]);
  }
}

extern "C" void kernel_launch(void* const* d_in, const int* in_sizes, int n_in,
                              void* d_out, int out_size, void* d_ws,
                              size_t ws_size, hipStream_t stream) {
  const float* x = (const float*)d_in[0];     // [32,64,160,160]
  const float* alpha = (const float*)d_in[1]; // [32,8]
  const float* ke = (const float*)d_in[2];    // [8,64,64,1,1]
  float* out = (float*)d_out;                 // [32,64,160,160]
  float* kt = (float*)d_ws;                   // 32*4096 floats = 512KB scratch

  mix_kernel<<<BATCH * 8, 256, 0, stream>>>(alpha, ke, kt);
  conv_kernel<<<GRID, 256, 0, stream>>>(x, kt, out);
}